// Round 2
// baseline (126.285 us; speedup 1.0000x reference)
//
#include <hip/hip_runtime.h>

// Causal dilated conv1d (dilation=64, K=2) + tanh*sigmoid gate via bf16 MFMA.
// v2 (resubmit — prior round was an infra failure, not a kernel verdict):
// persistent streaming blocks + LDS ring buffer.
//  - grid 1024 = exactly 4 blocks/CU (one uniform occupancy round; v1's
//    2048-block grid ran ragged 6-then-2 rounds at 24 KB LDS).
//  - each block owns 256 t of one batch, processed as 4 chunks of 64 t
//    against a 128-row x 64-ci bf16 ring (16 KB LDS, slot = g & 127).
//  - software pipeline (T14): next chunk's 64 rows are loaded to registers
//    BEFORE the current chunk's MFMA phase (latency hidden under compute),
//    packed+ds_written after the read barrier into the 64 slots just freed.
//  - epilogue of chunk k deferred into iteration k+1 so global stores drain
//    during compute, not at a barrier.
// w split hi/lo (2 MFMA terms, fp32-grade w); x single RNE bf16 (unchanged
// numerics vs v1, absmax ~0.007 vs 2e-2 threshold).
// y[b,co,t] = sum_ci w[co][ci][0]*x[b][ci][t-64] + w[co][ci][1]*x[b][ci][t]

#define B_ 16
#define C_ 64
#define T_ 16384
#define RING 128          // ring rows (power of 2), row = 64 bf16 = 128 B

typedef __attribute__((ext_vector_type(8))) short short8;
typedef __attribute__((ext_vector_type(4))) float f32x4;

union Frag { short8 s; unsigned u[4]; };

__device__ __forceinline__ unsigned bf16_rne(float f) {
    unsigned u = __float_as_uint(f);
    return (u + 0x7fffu + ((u >> 16) & 1u)) >> 16;
}

__device__ __forceinline__ unsigned pack_rne(float a, float b) {
    unsigned ua = __float_as_uint(a), ub = __float_as_uint(b);
    unsigned ra = ua + 0x7fffu + ((ua >> 16) & 1u);
    unsigned rb = ub + 0x7fffu + ((ub >> 16) & 1u);
    return (ra >> 16) | (rb & 0xffff0000u);
}

#define EPILOGUE(A, KK)                                                     \
    _Pragma("unroll")                                                       \
    for (int s = 0; s < 4; ++s) {                                           \
        _Pragma("unroll")                                                   \
        for (int r = 0; r < 4; ++r) {                                       \
            float y = (A)[s][r];                                            \
            y = fminf(fmaxf(y, -20.f), 20.f);                               \
            float e   = __expf(-y);                                         \
            float e2  = e * e;                                              \
            float num = 1.f - e2;                                           \
            float den = (1.f + e) * (1.f + e2);                             \
            ob[(size_t)(4 * q + r) * T_ + ((KK) * 64 + 16 * s + n)] =       \
                num * __builtin_amdgcn_rcpf(den);                           \
        }                                                                   \
    }

__global__ __launch_bounds__(256, 4) void conv_gate_ring(
    const float* __restrict__ x,
    const float* __restrict__ w,
    float* __restrict__ out)
{
    __shared__ unsigned short xs[RING * 64];   // 16384 B

    const int tid = threadIdx.x;
    const int bid = blockIdx.x;
    // XCD-bijective swizzle (1024 wgs, 8 XCDs): contiguous segs share an XCD
    // so halo rows of neighbor segments hit the same L2.
    const int wg  = (bid & 7) * 128 + (bid >> 3);
    const int b   = wg >> 6;          // batch
    const int seg = wg & 63;          // which 256-t segment
    const int t0  = seg << 8;
    const float* xb = x + (size_t)b * C_ * T_;

    // ---- prologue: issue loads for rows [t0-64, t0+64)  (ring slots (rr+64)&127)
    // task = (rr 0..127, c8 0..7); lanes consecutive in rr -> 256B coalesced.
    float pv[4][8];
    #pragma unroll
    for (int it = 0; it < 4; ++it) {
        const int task = it * 256 + tid;
        const int rr   = task & 127;
        const int c8   = task >> 7;          // 0..7
        const int g    = t0 - 64 + rr;
        if (g >= 0) {
            const float* xp = xb + (size_t)(8 * c8) * T_ + g;
            #pragma unroll
            for (int i = 0; i < 8; ++i) pv[it][i] = xp[(size_t)i * T_];
        } else {
            #pragma unroll
            for (int i = 0; i < 8; ++i) pv[it][i] = 0.f;
        }
    }

    // ---- per-wave w fragments (A-layout), hi/lo RNE split (overlaps x latency)
    const int lane = tid & 63;
    const int wid  = tid >> 6;
    const int m    = lane & 15;
    const int q    = lane >> 4;
    const int co   = wid * 16 + m;

    Frag wh[2][2], wl[2][2];   // [tap p][k-half h]
    #pragma unroll
    for (int h = 0; h < 2; ++h) {
        const float* wp = w + co * 128 + h * 64 + q * 16;
        float f[16];
        #pragma unroll
        for (int v4 = 0; v4 < 4; ++v4) {
            float4 t4 = *(const float4*)(wp + 4 * v4);
            f[4*v4+0] = t4.x; f[4*v4+1] = t4.y; f[4*v4+2] = t4.z; f[4*v4+3] = t4.w;
        }
        #pragma unroll
        for (int p = 0; p < 2; ++p) {
            #pragma unroll
            for (int d = 0; d < 4; ++d) {
                float e0 = f[2*(2*d)   + p];
                float e1 = f[2*(2*d+1) + p];
                unsigned h0 = bf16_rne(e0), h1 = bf16_rne(e1);
                float r0 = e0 - __uint_as_float(h0 << 16);
                float r1 = e1 - __uint_as_float(h1 << 16);
                wh[p][h].u[d] = h0 | (h1 << 16);
                wl[p][h].u[d] = bf16_rne(r0) | (bf16_rne(r1) << 16);
            }
        }
    }

    // ---- prologue pack + ring write
    #pragma unroll
    for (int it = 0; it < 4; ++it) {
        const int task = it * 256 + tid;
        const int rr   = task & 127;
        const int c8   = task >> 7;
        unsigned p0 = pack_rne(pv[it][0], pv[it][1]);
        unsigned p1 = pack_rne(pv[it][2], pv[it][3]);
        unsigned p2 = pack_rne(pv[it][4], pv[it][5]);
        unsigned p3 = pack_rne(pv[it][6], pv[it][7]);
        const int slot = (rr + 64) & 127;                    // slot = g & 127
        const int so   = slot * 64 + ((c8 ^ (rr & 7)) * 8);  // rr&7 == g&7
        *(uint4*)(&xs[so]) = make_uint4(p0, p1, p2, p3);
    }

    const int n   = m;
    const int swb = n & 7;
    float* ob = out + ((size_t)b * C_ + wid * 16) * T_ + t0;

    f32x4 acc2[2][4];          // double accumulator: epilogue(k-1) overlaps chunk k

    __syncthreads();

    // ---- 4 chunks of 64 t. Chunk k computes from ring window [c0-64, c0+64),
    // c0 = t0 + 64k; rows 16u+n-64: u<4 -> tap0 of subtile u, u>=4 -> tap1 of u-4.
    #pragma unroll
    for (int k = 0; k < 4; ++k) {
        // (1) prefetch next chunk's rows [t0 + 64(k+1), +64) into registers
        float v[2][8];
        if (k < 3) {
            #pragma unroll
            for (int it = 0; it < 2; ++it) {
                const int task = it * 256 + tid;
                const int rr = task & 63, c8 = task >> 6;
                const float* xp = xb + (size_t)(8 * c8) * T_ + (t0 + 64 * (k + 1) + rr);
                #pragma unroll
                for (int i = 0; i < 8; ++i) v[it][i] = xp[(size_t)i * T_];
            }
        }

        // (2) deferred epilogue of chunk k-1: stores drain during this compute
        if (k > 0) { EPILOGUE(acc2[(k & 1) ^ 1], k - 1); }

        // (3) compute chunk k
        f32x4* acc = acc2[k & 1];
        #pragma unroll
        for (int s = 0; s < 4; ++s) acc[s] = (f32x4){0.f, 0.f, 0.f, 0.f};
        const int kb = ((k & 1) ^ 1) << 6;   // (c0-64) & 127
        #pragma unroll
        for (int u = 0; u < 8; ++u) {
            const int rbase = ((kb + 16 * u + n) & 127) * 64;
            Frag f0, f1;
            f0.s = *(const short8*)(&xs[rbase + ((q ^ swb) * 8)]);        // ci 8q..
            f1.s = *(const short8*)(&xs[rbase + (((4 + q) ^ swb) * 8)]);  // ci 32+8q..
            if (u < 4) {
                acc[u] = __builtin_amdgcn_mfma_f32_16x16x32_bf16(wh[0][0].s, f0.s, acc[u], 0, 0, 0);
                acc[u] = __builtin_amdgcn_mfma_f32_16x16x32_bf16(wl[0][0].s, f0.s, acc[u], 0, 0, 0);
                acc[u] = __builtin_amdgcn_mfma_f32_16x16x32_bf16(wh[0][1].s, f1.s, acc[u], 0, 0, 0);
                acc[u] = __builtin_amdgcn_mfma_f32_16x16x32_bf16(wl[0][1].s, f1.s, acc[u], 0, 0, 0);
            } else {
                const int s2 = u - 4;
                acc[s2] = __builtin_amdgcn_mfma_f32_16x16x32_bf16(wh[1][0].s, f0.s, acc[s2], 0, 0, 0);
                acc[s2] = __builtin_amdgcn_mfma_f32_16x16x32_bf16(wl[1][0].s, f0.s, acc[s2], 0, 0, 0);
                acc[s2] = __builtin_amdgcn_mfma_f32_16x16x32_bf16(wh[1][1].s, f1.s, acc[s2], 0, 0, 0);
                acc[s2] = __builtin_amdgcn_mfma_f32_16x16x32_bf16(wl[1][1].s, f1.s, acc[s2], 0, 0, 0);
            }
        }

        if (k < 3) {
            __syncthreads();   // window-k reads done (also drains prefetch loads)

            // (4) pack + write next chunk into the 64 slots just freed
            #pragma unroll
            for (int it = 0; it < 2; ++it) {
                const int task = it * 256 + tid;
                const int rr = task & 63, c8 = task >> 6;
                unsigned p0 = pack_rne(v[it][0], v[it][1]);
                unsigned p1 = pack_rne(v[it][2], v[it][3]);
                unsigned p2 = pack_rne(v[it][4], v[it][5]);
                unsigned p3 = pack_rne(v[it][6], v[it][7]);
                const int slot = (64 * (k + 1) + rr) & 127;
                const int so   = slot * 64 + ((c8 ^ (rr & 7)) * 8);
                *(uint4*)(&xs[so]) = make_uint4(p0, p1, p2, p3);
            }

            __syncthreads();   // ring writes visible before next compute
        }
    }

    // epilogue of the last chunk
    EPILOGUE(acc2[1], 3);
}

extern "C" void kernel_launch(void* const* d_in, const int* in_sizes, int n_in,
                              void* d_out, int out_size, void* d_ws, size_t ws_size,
                              hipStream_t stream) {
    const float* x = (const float*)d_in[0];
    const float* w = (const float*)d_in[1];
    float* out = (float*)d_out;
    conv_gate_ring<<<dim3(1024), dim3(256), 0, stream>>>(x, w, out);
}